// Round 1
// baseline (6467.222 us; speedup 1.0000x reference)
//
#include <hip/hip_runtime.h>
#include <cstdint>
#include <cstddef>

#define G 64
#define L 512
#define D 256
#define NN 32768
#define EE 524288
#define DI 512

__device__ __forceinline__ float sigmoidf_(float x){ return 1.0f/(1.0f+__expf(-x)); }
__device__ __forceinline__ float siluf_(float x){ return x*sigmoidf_(x); }

// ---------------- degree ----------------
__global__ void deg_kernel(const int* __restrict__ ei, int* __restrict__ dout, int* __restrict__ din){
  int e = blockIdx.x*blockDim.x + threadIdx.x;
  if (e < EE){ atomicAdd(&dout[ei[e]],1); atomicAdd(&din[ei[EE+e]],1); }
}

// ---------------- per-graph stable argsort of out-degree (bitonic) ----------------
__global__ __launch_bounds__(512) void sort_kernel(const int* __restrict__ dout, int* __restrict__ perm, int* __restrict__ inv){
  __shared__ unsigned key[L];
  int g = blockIdx.x, i = threadIdx.x;
  key[i] = ((unsigned)dout[g*L+i] << 9) | (unsigned)i;
  __syncthreads();
  for (int k=2;k<=L;k<<=1)
    for (int j=k>>1;j>0;j>>=1){
      int ixj = i ^ j;
      if (ixj > i){
        unsigned a=key[i], b=key[ixj];
        bool up = ((i & k)==0);
        if (up ? (a>b) : (a<b)){ key[i]=b; key[ixj]=a; }
      }
      __syncthreads();
    }
  unsigned v = key[i] & 511u;
  perm[g*L+i] = (int)v;
  inv[g*L+(int)v] = i;
}

// ---------------- exclusive prefix sum over deg_in ----------------
__global__ __launch_bounds__(1024) void prefix_kernel(const int* __restrict__ deg, int* __restrict__ off, int n){
  __shared__ int buf[1024];
  __shared__ int carry;
  int tid = threadIdx.x;
  if (tid==0) carry = 0;
  __syncthreads();
  for (int base=0;base<n;base+=1024){
    int v = deg[base+tid];
    buf[tid]=v; __syncthreads();
    for (int s=1;s<1024;s<<=1){
      int t = (tid>=s)? buf[tid-s]:0;
      __syncthreads();
      buf[tid]+=t;
      __syncthreads();
    }
    off[base+tid] = carry + buf[tid] - v;
    __syncthreads();
    if (tid==1023) carry += buf[1023];
    __syncthreads();
  }
  if (tid==0) off[n] = carry;
}

__global__ void csr_fill(const int* __restrict__ ei, const int* __restrict__ off, int* __restrict__ cur, int* __restrict__ eid){
  int e = blockIdx.x*blockDim.x+threadIdx.x;
  if (e<EE){ int dn = ei[EE+e]; int p = atomicAdd(&cur[dn],1); eid[off[dn]+p] = e; }
}

// ---------------- generic f32 GEMM: C[M,Nc] = A[M,K]@B[K,Nc]; epilogues ----------------
// act: 0 none, 1 relu, 2 sigmoid, 3 gate (out = s*gA[r,c] + (1-s)*gA[r,256+c], gA stride 512)
__global__ __launch_bounds__(256) void gemm_k(
    const float* __restrict__ A, const float* __restrict__ B,
    const float* __restrict__ bias, const float* __restrict__ resid,
    const float* __restrict__ mulp, const float* __restrict__ gateA,
    float* __restrict__ C, int Nc, int K, int lda, int ldc, int act)
{
  __shared__ float As[16][68];
  __shared__ float Bs[16][68];
  int tid = threadIdx.x;
  int tx = tid & 15, ty = tid >> 4;
  int bm = blockIdx.y * 64, bn = blockIdx.x * 64;
  float acc[4][4] = {};
  int ar = tid >> 2, ak = (tid & 3) << 2;
  int bk = tid >> 4, bc = (tid & 15) << 2;
  for (int k0=0;k0<K;k0+=16){
    float4 av = *(const float4*)(A + (size_t)(bm+ar)*lda + k0 + ak);
    As[ak][ar]=av.x; As[ak+1][ar]=av.y; As[ak+2][ar]=av.z; As[ak+3][ar]=av.w;
    const float* bp = B + (size_t)(k0+bk)*Nc + bn + bc;
    float4 bv;
    if (bn + bc + 3 < Nc) bv = *(const float4*)bp;
    else {
      bv.x = (bn+bc+0<Nc)? bp[0]:0.f; bv.y = (bn+bc+1<Nc)? bp[1]:0.f;
      bv.z = (bn+bc+2<Nc)? bp[2]:0.f; bv.w = (bn+bc+3<Nc)? bp[3]:0.f;
    }
    Bs[bk][bc]=bv.x; Bs[bk][bc+1]=bv.y; Bs[bk][bc+2]=bv.z; Bs[bk][bc+3]=bv.w;
    __syncthreads();
    #pragma unroll
    for (int kk=0;kk<16;++kk){
      float4 a4 = *(const float4*)&As[kk][ty<<2];
      float4 b4 = *(const float4*)&Bs[kk][tx<<2];
      float a0=a4.x,a1=a4.y,a2=a4.z,a3=a4.w;
      float b0=b4.x,b1=b4.y,b2=b4.z,b3=b4.w;
      acc[0][0]=fmaf(a0,b0,acc[0][0]); acc[0][1]=fmaf(a0,b1,acc[0][1]); acc[0][2]=fmaf(a0,b2,acc[0][2]); acc[0][3]=fmaf(a0,b3,acc[0][3]);
      acc[1][0]=fmaf(a1,b0,acc[1][0]); acc[1][1]=fmaf(a1,b1,acc[1][1]); acc[1][2]=fmaf(a1,b2,acc[1][2]); acc[1][3]=fmaf(a1,b3,acc[1][3]);
      acc[2][0]=fmaf(a2,b0,acc[2][0]); acc[2][1]=fmaf(a2,b1,acc[2][1]); acc[2][2]=fmaf(a2,b2,acc[2][2]); acc[2][3]=fmaf(a2,b3,acc[2][3]);
      acc[3][0]=fmaf(a3,b0,acc[3][0]); acc[3][1]=fmaf(a3,b1,acc[3][1]); acc[3][2]=fmaf(a3,b2,acc[3][2]); acc[3][3]=fmaf(a3,b3,acc[3][3]);
    }
    __syncthreads();
  }
  #pragma unroll
  for (int i2=0;i2<4;++i2){
    int r = bm + (ty<<2) + i2;
    #pragma unroll
    for (int j2=0;j2<4;++j2){
      int c = bn + (tx<<2) + j2;
      if (c >= Nc) continue;
      float v = acc[i2][j2];
      if (bias) v += bias[c];
      if (resid) v += resid[(size_t)r*Nc + c];
      if (act==1) v = fmaxf(v,0.f);
      else if (act==2) v = sigmoidf_(v);
      else if (act==3){
        float s = sigmoidf_(v);
        v = s*gateA[(size_t)r*512+c] + (1.f-s)*gateA[(size_t)r*512+256+c];
      }
      if (mulp) v *= mulp[(size_t)r*Nc + c];
      C[(size_t)r*ldc + c] = v;
    }
  }
}

// ---------------- causal depthwise conv (seq order) + silu ----------------
__global__ __launch_bounds__(512) void conv_kernel(const float* __restrict__ xz, const float* __restrict__ convw,
    const float* __restrict__ convb, const int* __restrict__ perm, float* __restrict__ xc, int dir){
  int t = blockIdx.x, g = blockIdx.y, d = threadIdx.x;
  float acc = convb[d];
  #pragma unroll
  for (int j=0;j<4;++j){
    int tt = t - 3 + j;
    if (tt < 0) continue;
    int row;
    if (dir==0) row = tt;
    else if (dir==1) row = L-1-tt;
    else if (dir==2) row = perm[g*L+tt];
    else row = perm[g*L + (L-1-tt)];
    acc = fmaf(convw[d*4+j], xz[((size_t)(g*L+row))*1024 + d], acc);
  }
  xc[((size_t)(g*L+t))*512 + d] = siluf_(acc);
}

// ---------------- selective scan (fused dt-GEMM, state scan, z-gate) ----------------
__global__ __launch_bounds__(128) void scan_kernel(
    const float* __restrict__ xc, const float* __restrict__ dbl,
    const float* __restrict__ xz, const float* __restrict__ Wdt,
    const float* __restrict__ bdt, const float* __restrict__ Alog,
    const float* __restrict__ Dp, const int* __restrict__ perm,
    float* __restrict__ yout, int dir)
{
  int g = blockIdx.y;
  int d = blockIdx.x*128 + threadIdx.x;
  float Av[16], wdt[16], h[16];
  #pragma unroll
  for (int s=0;s<16;++s){ Av[s] = -__expf(Alog[d*16+s]); h[s]=0.f; }
  #pragma unroll
  for (int r=0;r<16;++r) wdt[r] = Wdt[r*512+d];
  float bd = bdt[d], dp = Dp[d];
  for (int t=0;t<L;++t){
    const float* dr = dbl + (size_t)(g*L+t)*48;
    float draw = bd;
    #pragma unroll
    for (int r=0;r<16;++r) draw = fmaf(dr[r], wdt[r], draw);
    float dt = (draw > 20.f) ? draw : log1pf(__expf(draw));
    float xv = xc[(size_t)(g*L+t)*512 + d];
    float cb = dt*xv;
    float y = 0.f;
    #pragma unroll
    for (int s=0;s<16;++s){
      float e = __expf(dt*Av[s]);
      h[s] = fmaf(h[s], e, cb*dr[16+s]);
      y = fmaf(h[s], dr[32+s], y);
    }
    int row;
    if (dir==0) row=t; else if (dir==1) row=L-1-t;
    else if (dir==2) row=perm[g*L+t]; else row=perm[g*L+(L-1-t)];
    float zv = xz[((size_t)(g*L+row))*1024 + 512 + d];
    yout[(size_t)(g*L+t)*512 + d] = (y + xv*dp) * siluf_(zv);
  }
}

// ---------------- build [f|b] concat matrices for gating ----------------
__global__ __launch_bounds__(256) void gatecat_kernel(const float* __restrict__ o0, const float* __restrict__ o1,
    const float* __restrict__ o2, const float* __restrict__ o3,
    float* __restrict__ ufub, float* __restrict__ sfsb){
  int i = blockIdx.x, g = blockIdx.y, d = threadIdx.x;
  size_t rf = (size_t)(g*L+i);
  size_t rb = (size_t)(g*L+(L-1-i));
  ufub[rf*512 + d]       = o0[rf*256+d];
  ufub[rf*512 + 256 + d] = o1[rb*256+d];
  sfsb[rf*512 + d]       = o2[rf*256+d];
  sfsb[rf*512 + 256 + d] = o3[rb*256+d];
}

__global__ __launch_bounds__(256) void unsort_kernel(const float* __restrict__ ysort, const int* __restrict__ inv, float* __restrict__ ydst){
  int i = blockIdx.x, g = blockIdx.y, d = threadIdx.x;
  int j = inv[g*L+i];
  ydst[(size_t)(g*L+i)*256+d] = ysort[(size_t)(g*L+j)*256+d];
}

// ---------------- layernorm (row of 256) ----------------
__global__ __launch_bounds__(256) void ln_kernel(const float* __restrict__ src, float* __restrict__ dst,
    const float* __restrict__ gam, const float* __restrict__ bet){
  __shared__ float red[256];
  int row = blockIdx.x, d = threadIdx.x;
  float v = src[(size_t)row*256+d];
  red[d]=v; __syncthreads();
  for (int s=128;s>0;s>>=1){ if (d<s) red[d]+=red[d+s]; __syncthreads(); }
  float m = red[0]*(1.f/256.f);
  __syncthreads();
  float c = v-m;
  red[d]=c*c; __syncthreads();
  for (int s=128;s>0;s>>=1){ if (d<s) red[d]+=red[d+s]; __syncthreads(); }
  float var = red[0]*(1.f/256.f);
  dst[(size_t)row*256+d] = c*rsqrtf(var+1e-5f)*gam[d]+bet[d];
}

// ---------------- softmax-2 weighted combine (pw / mc) ----------------
__global__ __launch_bounds__(256) void combine2_kernel(const float* __restrict__ u, const float* __restrict__ s,
    const float* __restrict__ W, const float* __restrict__ bb, float* __restrict__ out){
  int wv = threadIdx.x >> 6, lane = threadIdx.x & 63;
  int row = blockIdx.x*4 + wv;
  float a0=0.f, a1=0.f;
  float uv[4], sv[4];
  #pragma unroll
  for (int q=0;q<4;++q){
    int c = lane + q*64;
    float uu = u[(size_t)row*256+c], ss = s[(size_t)row*256+c];
    uv[q]=uu; sv[q]=ss;
    a0 = fmaf(uu, W[2*c], a0);   a0 = fmaf(ss, W[2*(c+256)], a0);
    a1 = fmaf(uu, W[2*c+1], a1); a1 = fmaf(ss, W[2*(c+256)+1], a1);
  }
  for (int o=32;o;o>>=1){ a0 += __shfl_xor(a0,o); a1 += __shfl_xor(a1,o); }
  a0 += bb[0]; a1 += bb[1];
  float mx = fmaxf(a0,a1);
  float e0 = __expf(a0-mx), e1 = __expf(a1-mx);
  float w0 = e0/(e0+e1), w1 = 1.f - w0;
  #pragma unroll
  for (int q=0;q<4;++q){
    int c = lane + q*64;
    out[(size_t)row*256+c] = w0*uv[q] + w1*sv[q];
  }
}

// ---------------- GCN layer-1 aggregation (512-wide, relu+deg-norm) ----------------
__global__ __launch_bounds__(256) void agg512_kernel(const float* __restrict__ m1, const int* __restrict__ off,
    const int* __restrict__ eid, const int* __restrict__ ei, const int* __restrict__ din,
    float* __restrict__ t1){
  int wv = threadIdx.x >> 6, lane = threadIdx.x & 63;
  int n = blockIdx.x*4 + wv;
  int c = lane*8;
  float4 A0 = {0,0,0,0}, A1 = {0,0,0,0};
  int p0 = off[n], p1 = off[n+1];
  for (int p=p0;p<p1;++p){
    int e = eid[p];
    int sN = ei[e];
    const float* rp = m1 + (size_t)sN*512 + c;
    float4 v0 = *(const float4*)rp, v1 = *(const float4*)(rp+4);
    A0.x+=v0.x; A0.y+=v0.y; A0.z+=v0.z; A0.w+=v0.w;
    A1.x+=v1.x; A1.y+=v1.y; A1.z+=v1.z; A1.w+=v1.w;
  }
  const float* sp = m1 + (size_t)n*512 + c;
  float4 v0 = *(const float4*)sp, v1 = *(const float4*)(sp+4);
  A0.x+=v0.x; A0.y+=v0.y; A0.z+=v0.z; A0.w+=v0.w;
  A1.x+=v1.x; A1.y+=v1.y; A1.z+=v1.z; A1.w+=v1.w;
  float sc = 1.f/((float)din[n]+1.f);
  float* op = t1 + (size_t)n*512 + c;
  op[0]=fmaxf(A0.x*sc,0.f); op[1]=fmaxf(A0.y*sc,0.f); op[2]=fmaxf(A0.z*sc,0.f); op[3]=fmaxf(A0.w*sc,0.f);
  op[4]=fmaxf(A1.x*sc,0.f); op[5]=fmaxf(A1.y*sc,0.f); op[6]=fmaxf(A1.z*sc,0.f); op[7]=fmaxf(A1.w*sc,0.f);
}

// ---------------- layer-2 projections (both chains, 4 outputs) ----------------
__global__ __launch_bounds__(256) void m2_kernel(const float* __restrict__ t1, const float* __restrict__ Wi,
    const float* __restrict__ Wo, float* __restrict__ m2){
  int wv = threadIdx.x>>6, lane = threadIdx.x&63;
  int row = blockIdx.x*4+wv;
  float a[4]={0,0,0,0};
  #pragma unroll
  for (int q=0;q<4;++q){
    int c = lane + q*64;
    float ti = t1[(size_t)row*512 + c];
    float to = t1[(size_t)row*512 + 256 + c];
    a[0]=fmaf(ti,Wi[2*c],a[0]); a[1]=fmaf(ti,Wi[2*c+1],a[1]);
    a[2]=fmaf(to,Wo[2*c],a[2]); a[3]=fmaf(to,Wo[2*c+1],a[3]);
  }
  for (int o=32;o;o>>=1){
    a[0]+=__shfl_xor(a[0],o); a[1]+=__shfl_xor(a[1],o);
    a[2]+=__shfl_xor(a[2],o); a[3]+=__shfl_xor(a[3],o);
  }
  if (lane==0){ float4 v={a[0],a[1],a[2],a[3]}; *(float4*)(m2+(size_t)row*4)=v; }
}

__global__ void p_kernel(const float* __restrict__ m2, const int* __restrict__ off, const int* __restrict__ eid,
    const int* __restrict__ ei, const int* __restrict__ din, float* __restrict__ pin, float* __restrict__ pout){
  int n = blockIdx.x*blockDim.x + threadIdx.x;
  if (n>=NN) return;
  float4 acc = *(const float4*)(m2 + (size_t)n*4);
  for (int p=off[n];p<off[n+1];++p){
    int e = eid[p]; int sN = ei[e];
    float4 v = *(const float4*)(m2+(size_t)sN*4);
    acc.x+=v.x; acc.y+=v.y; acc.z+=v.z; acc.w+=v.w;
  }
  float sc = 1.f/((float)din[n]+1.f);
  float a0=acc.x*sc, a1=acc.y*sc, b0=acc.z*sc, b1=acc.w*sc;
  {
    float mx=fmaxf(a0,a1); float e0=__expf(a0-mx), e1=__expf(a1-mx);
    pin[n] = e0/(e0+e1);
  }
  {
    float mx=fmaxf(b0,b1); float e0=__expf(b0-mx), e1=__expf(b1-mx);
    pout[n] = e0/(e0+e1);
  }
}

__global__ void ew_kernel(const int* __restrict__ ei, const float* __restrict__ pin, const float* __restrict__ pout,
    float* __restrict__ ew){
  int e = blockIdx.x*blockDim.x+threadIdx.x;
  if (e<EE) ew[e] = pin[ei[EE+e]] * pout[ei[e]];
}

// ---------------- weighted aggregation of edge_attr and m_env[src] ----------------
__global__ __launch_bounds__(256) void wagg_kernel(const float* __restrict__ eattr, const float* __restrict__ menv,
    const float* __restrict__ ew, const int* __restrict__ off, const int* __restrict__ eid,
    const int* __restrict__ ei, float* __restrict__ aat, float* __restrict__ aen){
  int wv=threadIdx.x>>6, lane=threadIdx.x&63;
  int n = blockIdx.x*4+wv;
  int c = lane*4;
  float4 A={0,0,0,0}, En={0,0,0,0};
  int p0=off[n], p1=off[n+1];
  for (int p=p0;p<p1;++p){
    int e = eid[p]; float w = ew[e]; int sN = ei[e];
    float4 av = *(const float4*)(eattr + (size_t)e*256 + c);
    float4 ev = *(const float4*)(menv + (size_t)sN*256 + c);
    A.x=fmaf(w,av.x,A.x); A.y=fmaf(w,av.y,A.y); A.z=fmaf(w,av.z,A.z); A.w=fmaf(w,av.w,A.w);
    En.x=fmaf(w,ev.x,En.x); En.y=fmaf(w,ev.y,En.y); En.z=fmaf(w,ev.z,En.z); En.w=fmaf(w,ev.w,En.w);
  }
  *(float4*)(aat+(size_t)n*256+c)=A;
  *(float4*)(aen+(size_t)n*256+c)=En;
}

// ---------------- cognn: combine + relu + LN ----------------
__global__ __launch_bounds__(256) void cognn_kernel(const float* __restrict__ aen, const float* __restrict__ aw,
    const float* __restrict__ menv, const int* __restrict__ din, const float* __restrict__ envb,
    const float* __restrict__ gam, const float* __restrict__ bet, float* __restrict__ out){
  __shared__ float red[256];
  int row=blockIdx.x, d=threadIdx.x;
  float sc = 1.f/((float)din[row]+1.f);
  float v = (aen[(size_t)row*256+d] + aw[(size_t)row*256+d] + menv[(size_t)row*256+d]) * sc + envb[d];
  v = fmaxf(v,0.f);
  red[d]=v; __syncthreads();
  for (int s=128;s>0;s>>=1){ if (d<s) red[d]+=red[d+s]; __syncthreads(); }
  float m = red[0]*(1.f/256.f);
  __syncthreads();
  float c = v-m;
  red[d]=c*c; __syncthreads();
  for (int s=128;s>0;s>>=1){ if (d<s) red[d]+=red[d+s]; __syncthreads(); }
  float var = red[0]*(1.f/256.f);
  out[(size_t)row*256+d] = c*rsqrtf(var+1e-5f)*gam[d]+bet[d];
}

// =====================================================================
extern "C" void kernel_launch(void* const* d_in, const int* in_sizes, int n_in,
                              void* d_out, int out_size, void* d_ws, size_t ws_size,
                              hipStream_t stream) {
  const float* x       = (const float*)d_in[0];
  const int*   ei      = (const int*)d_in[1];
  const float* eattr   = (const float*)d_in[2];
  const float* m_Win   = (const float*)d_in[4];
  const float* m_convw = (const float*)d_in[5];
  const float* m_convb = (const float*)d_in[6];
  const float* m_Wx    = (const float*)d_in[7];
  const float* m_Wdt   = (const float*)d_in[8];
  const float* m_bdt   = (const float*)d_in[9];
  const float* m_Alog  = (const float*)d_in[10];
  const float* m_Dp    = (const float*)d_in[11];
  const float* m_Wout  = (const float*)d_in[12];
  const float* gate_u_W= (const float*)d_in[13];
  const float* gate_u_b= (const float*)d_in[14];
  const float* gate_s_W= (const float*)d_in[15];
  const float* gate_s_b= (const float*)d_in[16];
  const float* fn_g    = (const float*)d_in[17];
  const float* fn_b    = (const float*)d_in[18];
  const float* on_g    = (const float*)d_in[19];
  const float* on_b    = (const float*)d_in[20];
  const float* pw_W    = (const float*)d_in[21];
  const float* pw_b    = (const float*)d_in[22];
  const float* mc_W    = (const float*)d_in[23];
  const float* mc_b    = (const float*)d_in[24];
  const float* ca_W1   = (const float*)d_in[25];
  const float* ca_b1   = (const float*)d_in[26];
  const float* ca_W2   = (const float*)d_in[27];
  const float* ca_b2   = (const float*)d_in[28];
  const float* fe_W1   = (const float*)d_in[29];
  const float* fe_b1   = (const float*)d_in[30];
  const float* fe_W2   = (const float*)d_in[31];
  const float* fe_b2   = (const float*)d_in[32];
  const float* in_W1   = (const float*)d_in[33];
  const float* in_W2   = (const float*)d_in[34];
  const float* out_W1  = (const float*)d_in[35];
  const float* out_W2  = (const float*)d_in[36];
  const float* env_W   = (const float*)d_in[37];
  const float* env_b   = (const float*)d_in[38];
  const float* edge_W  = (const float*)d_in[39];

  char* w = (char*)d_ws;
  size_t o = 0;
  auto alignup = [&](){ o = (o + 255) & ~(size_t)255; };
  auto F = [&](size_t n){ alignup(); float* p=(float*)(w+o); o+=n*sizeof(float); return p; };
  auto Ii = [&](size_t n){ alignup(); int* p=(int*)(w+o); o+=n*sizeof(int); return p; };

  int* deg_out = Ii(NN);
  int* deg_in  = Ii(NN);
  int* permB   = Ii(NN);
  int* invB    = Ii(NN);
  int* csr_off = Ii(NN+1);
  int* csr_cur = Ii(NN);
  int* csr_eid = Ii(EE);
  float* ew    = F(EE);
  float* m2cat = F((size_t)NN*4);
  float* p_in  = F(NN);
  float* p_out = F(NN);
  float* dbl   = F((size_t)NN*48);
  float* a1b   = F((size_t)NN*64);
  float* bufA  = F((size_t)NN*1024);
  float* bufB  = F((size_t)NN*512);
  float* bufC  = F((size_t)NN*512);
  float* outs  = F((size_t)NN*1024);

  float* A0 = bufA;                 // slots of N*256
  float* A1 = bufA + (size_t)NN*256;
  float* A2 = bufA + (size_t)NN*512;
  float* A3 = bufA + (size_t)NN*768;
  float* B0 = bufB;
  float* B1 = bufB + (size_t)NN*256;
  float* O0 = outs;
  float* O1 = outs + (size_t)NN*256;
  float* O2 = outs + (size_t)NN*512;
  float* O3 = outs + (size_t)NN*768;

  // ---- graph structure ----
  hipMemsetAsync(deg_out, 0, NN*sizeof(int), stream);
  hipMemsetAsync(deg_in,  0, NN*sizeof(int), stream);
  hipMemsetAsync(csr_cur, 0, NN*sizeof(int), stream);
  deg_kernel<<<EE/256, 256, 0, stream>>>(ei, deg_out, deg_in);
  sort_kernel<<<G, 512, 0, stream>>>(deg_out, permB, invB);
  prefix_kernel<<<1, 1024, 0, stream>>>(deg_in, csr_off, NN);
  csr_fill<<<EE/256, 256, 0, stream>>>(ei, csr_off, csr_cur, csr_eid);

  // ---- mamba: 4 directions ----
  for (int k=0;k<4;++k){
    gemm_k<<<dim3(16,512), 256, 0, stream>>>(x, m_Win + (size_t)k*256*1024,
        nullptr, nullptr, nullptr, nullptr, bufA, 1024, 256, 256, 1024, 0);
    conv_kernel<<<dim3(L,G), 512, 0, stream>>>(bufA, m_convw + (size_t)k*512*4,
        m_convb + (size_t)k*512, permB, bufB, k);
    gemm_k<<<dim3(1,512), 256, 0, stream>>>(bufB, m_Wx + (size_t)k*512*48,
        nullptr, nullptr, nullptr, nullptr, dbl, 48, 512, 512, 48, 0);
    scan_kernel<<<dim3(4,G), 128, 0, stream>>>(bufB, dbl, bufA,
        m_Wdt + (size_t)k*16*512, m_bdt + (size_t)k*512, m_Alog + (size_t)k*512*16,
        m_Dp + (size_t)k*512, permB, bufC, k);
    gemm_k<<<dim3(4,512), 256, 0, stream>>>(bufC, m_Wout + (size_t)k*512*256,
        nullptr, nullptr, nullptr, nullptr, outs + (size_t)k*NN*256, 256, 512, 512, 256, 0);
  }

  // ---- bidirectional gating ----
  gatecat_kernel<<<dim3(L,G), 256, 0, stream>>>(O0, O1, O2, O3, bufB, bufC);
  gemm_k<<<dim3(4,512), 256, 0, stream>>>(bufB, gate_u_W, gate_u_b, nullptr, nullptr, bufB,
      A0, 256, 512, 512, 256, 3);                         // y_u
  gemm_k<<<dim3(4,512), 256, 0, stream>>>(bufC, gate_s_W, gate_s_b, nullptr, nullptr, bufC,
      A1, 256, 512, 512, 256, 3);                         // y_s_sorted
  unsort_kernel<<<dim3(L,G), 256, 0, stream>>>(A1, invB, A2);  // y_s
  ln_kernel<<<NN, 256, 0, stream>>>(A0, O0, fn_g, fn_b);       // unsorted_out
  ln_kernel<<<NN, 256, 0, stream>>>(A2, O1, fn_g, fn_b);       // sorted_out
  combine2_kernel<<<NN/4, 256, 0, stream>>>(O0, O1, pw_W, pw_b, A3);  // mamba_out

  // ---- GCN probability chains ----
  gemm_k<<<dim3(4,512), 256, 0, stream>>>(x, in_W1, nullptr, nullptr, nullptr, nullptr,
      bufB, 256, 256, 256, 512, 0);
  gemm_k<<<dim3(4,512), 256, 0, stream>>>(x, out_W1, nullptr, nullptr, nullptr, nullptr,
      bufB + 256, 256, 256, 256, 512, 0);
  agg512_kernel<<<NN/4, 256, 0, stream>>>(bufB, csr_off, csr_eid, ei, deg_in, bufC);
  m2_kernel<<<NN/4, 256, 0, stream>>>(bufC, in_W2, out_W2, m2cat);
  p_kernel<<<NN/256, 256, 0, stream>>>(m2cat, csr_off, csr_eid, ei, deg_in, p_in, p_out);

  // ---- CoGNN environment branch ----
  gemm_k<<<dim3(4,512), 256, 0, stream>>>(x, env_W, nullptr, nullptr, nullptr, nullptr,
      O0, 256, 256, 256, 256, 0);                        // m_env
  ew_kernel<<<EE/256, 256, 0, stream>>>(ei, p_in, p_out, ew);
  wagg_kernel<<<NN/4, 256, 0, stream>>>(eattr, O0, ew, csr_off, csr_eid, ei, O1, O2); // agg_attr, agg_env
  gemm_k<<<dim3(4,512), 256, 0, stream>>>(O1, edge_W, nullptr, nullptr, nullptr, nullptr,
      O3, 256, 256, 256, 256, 0);                        // agg_attr @ edge_W
  cognn_kernel<<<NN, 256, 0, stream>>>(O2, O3, O0, deg_in, env_b, fn_g, fn_b, A0); // cognn

  // ---- channel attention + fusion ----
  gemm_k<<<dim3(1,512), 256, 0, stream>>>(A3, ca_W1, ca_b1, nullptr, nullptr, nullptr,
      a1b, 64, 256, 256, 64, 1);
  gemm_k<<<dim3(4,512), 256, 0, stream>>>(a1b, ca_W2, ca_b2, nullptr, A3, nullptr,
      B0, 256, 64, 64, 256, 2);                          // mo
  gemm_k<<<dim3(1,512), 256, 0, stream>>>(A0, ca_W1, ca_b1, nullptr, nullptr, nullptr,
      a1b, 64, 256, 256, 64, 1);
  gemm_k<<<dim3(4,512), 256, 0, stream>>>(a1b, ca_W2, ca_b2, nullptr, A0, nullptr,
      B1, 256, 64, 64, 256, 2);                          // co
  combine2_kernel<<<NN/4, 256, 0, stream>>>(B0, B1, mc_W, mc_b, O0);   // out

  // ---- feedforward + residual + final LN ----
  gemm_k<<<dim3(4,512), 256, 0, stream>>>(O0, fe_W1, fe_b1, nullptr, nullptr, nullptr,
      O1, 256, 256, 256, 256, 1);
  gemm_k<<<dim3(4,512), 256, 0, stream>>>(O1, fe_W2, fe_b2, x, nullptr, nullptr,
      A1, 256, 256, 256, 256, 0);
  ln_kernel<<<NN, 256, 0, stream>>>(A1, (float*)d_out, on_g, on_b);
}

// Round 2
// 5041.816 us; speedup vs baseline: 1.2827x; 1.2827x over previous
//
#include <hip/hip_runtime.h>
#include <hip/hip_bf16.h>
#include <cstdint>
#include <cstddef>

#define G 64
#define L 512
#define D 256
#define NN 32768
#define EE 524288
#define DI 512

__device__ __forceinline__ float sigmoidf_(float x){ return 1.0f/(1.0f+__expf(-x)); }
__device__ __forceinline__ float siluf_(float x){ return x*sigmoidf_(x); }

// ---------------- degree ----------------
__global__ void deg_kernel(const int* __restrict__ ei, int* __restrict__ dout, int* __restrict__ din){
  int e = blockIdx.x*blockDim.x + threadIdx.x;
  if (e < EE){ atomicAdd(&dout[ei[e]],1); atomicAdd(&din[ei[EE+e]],1); }
}

// ---------------- per-graph stable argsort of out-degree (bitonic) ----------------
__global__ __launch_bounds__(512) void sort_kernel(const int* __restrict__ dout, int* __restrict__ perm, int* __restrict__ inv){
  __shared__ unsigned key[L];
  int g = blockIdx.x, i = threadIdx.x;
  key[i] = ((unsigned)dout[g*L+i] << 9) | (unsigned)i;
  __syncthreads();
  for (int k=2;k<=L;k<<=1)
    for (int j=k>>1;j>0;j>>=1){
      int ixj = i ^ j;
      if (ixj > i){
        unsigned a=key[i], b=key[ixj];
        bool up = ((i & k)==0);
        if (up ? (a>b) : (a<b)){ key[i]=b; key[ixj]=a; }
      }
      __syncthreads();
    }
  unsigned v = key[i] & 511u;
  perm[g*L+i] = (int)v;
  inv[g*L+(int)v] = i;
}

// ---------------- exclusive prefix sum over deg_in ----------------
__global__ __launch_bounds__(1024) void prefix_kernel(const int* __restrict__ deg, int* __restrict__ off, int n){
  __shared__ int buf[1024];
  __shared__ int carry;
  int tid = threadIdx.x;
  if (tid==0) carry = 0;
  __syncthreads();
  for (int base=0;base<n;base+=1024){
    int v = deg[base+tid];
    buf[tid]=v; __syncthreads();
    for (int s=1;s<1024;s<<=1){
      int t = (tid>=s)? buf[tid-s]:0;
      __syncthreads();
      buf[tid]+=t;
      __syncthreads();
    }
    off[base+tid] = carry + buf[tid] - v;
    __syncthreads();
    if (tid==1023) carry += buf[1023];
    __syncthreads();
  }
  if (tid==0) off[n] = carry;
}

__global__ void csr_fill(const int* __restrict__ ei, const int* __restrict__ off, int* __restrict__ cur, int* __restrict__ eid){
  int e = blockIdx.x*blockDim.x+threadIdx.x;
  if (e<EE){ int dn = ei[EE+e]; int p = atomicAdd(&cur[dn],1); eid[off[dn]+p] = e; }
}

// ---------------- generic f32 GEMM: C[M,Nc] = A[M,K]@B[K,Nc]; epilogues ----------------
// act: 0 none, 1 relu, 2 sigmoid, 3 gate (out = s*gA[r,c] + (1-s)*gA[r,256+c], gA stride 512)
__global__ __launch_bounds__(256) void gemm_k(
    const float* __restrict__ A, const float* __restrict__ B,
    const float* __restrict__ bias, const float* __restrict__ resid,
    const float* __restrict__ mulp, const float* __restrict__ gateA,
    float* __restrict__ C, int Nc, int K, int lda, int ldc, int act)
{
  __shared__ float As[16][68];
  __shared__ float Bs[16][68];
  int tid = threadIdx.x;
  int tx = tid & 15, ty = tid >> 4;
  int bm = blockIdx.y * 64, bn = blockIdx.x * 64;
  float acc[4][4] = {};
  int ar = tid >> 2, ak = (tid & 3) << 2;
  int bk = tid >> 4, bc = (tid & 15) << 2;
  for (int k0=0;k0<K;k0+=16){
    float4 av = *(const float4*)(A + (size_t)(bm+ar)*lda + k0 + ak);
    As[ak][ar]=av.x; As[ak+1][ar]=av.y; As[ak+2][ar]=av.z; As[ak+3][ar]=av.w;
    const float* bp = B + (size_t)(k0+bk)*Nc + bn + bc;
    float4 bv;
    if (bn + bc + 3 < Nc) bv = *(const float4*)bp;
    else {
      bv.x = (bn+bc+0<Nc)? bp[0]:0.f; bv.y = (bn+bc+1<Nc)? bp[1]:0.f;
      bv.z = (bn+bc+2<Nc)? bp[2]:0.f; bv.w = (bn+bc+3<Nc)? bp[3]:0.f;
    }
    Bs[bk][bc]=bv.x; Bs[bk][bc+1]=bv.y; Bs[bk][bc+2]=bv.z; Bs[bk][bc+3]=bv.w;
    __syncthreads();
    #pragma unroll
    for (int kk=0;kk<16;++kk){
      float4 a4 = *(const float4*)&As[kk][ty<<2];
      float4 b4 = *(const float4*)&Bs[kk][tx<<2];
      float a0=a4.x,a1=a4.y,a2=a4.z,a3=a4.w;
      float b0=b4.x,b1=b4.y,b2=b4.z,b3=b4.w;
      acc[0][0]=fmaf(a0,b0,acc[0][0]); acc[0][1]=fmaf(a0,b1,acc[0][1]); acc[0][2]=fmaf(a0,b2,acc[0][2]); acc[0][3]=fmaf(a0,b3,acc[0][3]);
      acc[1][0]=fmaf(a1,b0,acc[1][0]); acc[1][1]=fmaf(a1,b1,acc[1][1]); acc[1][2]=fmaf(a1,b2,acc[1][2]); acc[1][3]=fmaf(a1,b3,acc[1][3]);
      acc[2][0]=fmaf(a2,b0,acc[2][0]); acc[2][1]=fmaf(a2,b1,acc[2][1]); acc[2][2]=fmaf(a2,b2,acc[2][2]); acc[2][3]=fmaf(a2,b3,acc[2][3]);
      acc[3][0]=fmaf(a3,b0,acc[3][0]); acc[3][1]=fmaf(a3,b1,acc[3][1]); acc[3][2]=fmaf(a3,b2,acc[3][2]); acc[3][3]=fmaf(a3,b3,acc[3][3]);
    }
    __syncthreads();
  }
  #pragma unroll
  for (int i2=0;i2<4;++i2){
    int r = bm + (ty<<2) + i2;
    #pragma unroll
    for (int j2=0;j2<4;++j2){
      int c = bn + (tx<<2) + j2;
      if (c >= Nc) continue;
      float v = acc[i2][j2];
      if (bias) v += bias[c];
      if (resid) v += resid[(size_t)r*Nc + c];
      if (act==1) v = fmaxf(v,0.f);
      else if (act==2) v = sigmoidf_(v);
      else if (act==3){
        float s = sigmoidf_(v);
        v = s*gateA[(size_t)r*512+c] + (1.f-s)*gateA[(size_t)r*512+256+c];
      }
      if (mulp) v *= mulp[(size_t)r*Nc + c];
      C[(size_t)r*ldc + c] = v;
    }
  }
}

// ---------------- causal depthwise conv + silu; also emits silu(z) as bf16 ----------------
__global__ __launch_bounds__(512) void conv_kernel(const float* __restrict__ xz, const float* __restrict__ convw,
    const float* __restrict__ convb, const int* __restrict__ perm, float* __restrict__ xc,
    __hip_bfloat16* __restrict__ sz, int dir){
  int t = blockIdx.x, g = blockIdx.y, d = threadIdx.x;
  float acc = convb[d];
  #pragma unroll
  for (int j=0;j<4;++j){
    int tt = t - 3 + j;
    if (tt < 0) continue;
    int row;
    if (dir==0) row = tt;
    else if (dir==1) row = L-1-tt;
    else if (dir==2) row = perm[g*L+tt];
    else row = perm[g*L + (L-1-tt)];
    acc = fmaf(convw[d*4+j], xz[((size_t)(g*L+row))*1024 + d], acc);
  }
  xc[((size_t)(g*L+t))*512 + d] = siluf_(acc);
  // z-gate for this NODE row (storage is node-order; scan maps row at read time)
  float zv = xz[((size_t)(g*L+t))*1024 + 512 + d];
  sz[((size_t)(g*L+t))*512 + d] = __float2bfloat16(siluf_(zv));
}

// ---------------- selective scan: ALL 4 dirs, 2 threads/channel (8 states each) --------
// writes gated y IN-PLACE over xc4
__global__ __launch_bounds__(256) void scan4_kernel(
    float* __restrict__ xc4, const float* __restrict__ dbl4,
    const __hip_bfloat16* __restrict__ sz4,
    const float* __restrict__ Wdt, const float* __restrict__ bdt,
    const float* __restrict__ Alog, const float* __restrict__ Dp,
    const int* __restrict__ perm)
{
  int dir = blockIdx.z, g = blockIdx.y;
  int half = threadIdx.x & 1;
  int d = blockIdx.x*128 + (threadIdx.x >> 1);
  const float* Wd = Wdt + (size_t)dir*16*512;
  const float* Al = Alog + (size_t)dir*512*16 + d*16 + half*8;
  float Av[8], h[8], wdt[16];
  #pragma unroll
  for (int s=0;s<8;++s){ Av[s] = -__expf(Al[s]); h[s]=0.f; }
  #pragma unroll
  for (int r=0;r<16;++r) wdt[r] = Wd[r*512+d];
  float bd = bdt[dir*512+d], dp = Dp[dir*512+d];
  float* xcp = xc4 + (size_t)dir*NN*512 + (size_t)g*L*512;
  const float* dblp = dbl4 + (size_t)dir*NN*48 + (size_t)g*L*48;
  const __hip_bfloat16* szp = sz4 + (size_t)dir*NN*512 + (size_t)g*L*512;
  const int* pg = perm + g*L;
  int bofs = 16 + half*8, cofs = 32 + half*8;
  for (int t=0;t<L;++t){
    const float* dr = dblp + (size_t)t*48;
    float draw = bd;
    #pragma unroll
    for (int r=0;r<16;++r) draw = fmaf(dr[r], wdt[r], draw);
    float dt = (draw > 20.f) ? draw : log1pf(__expf(draw));
    float xv = xcp[(size_t)t*512 + d];
    float cb = dt*xv;
    float y = 0.f;
    #pragma unroll
    for (int s=0;s<8;++s){
      float e = __expf(dt*Av[s]);
      h[s] = fmaf(h[s], e, cb*dr[bofs+s]);
      y = fmaf(h[s], dr[cofs+s], y);
    }
    y += __shfl_xor(y, 1);
    if (half==0){
      int row;
      if (dir==0) row=t; else if (dir==1) row=L-1-t;
      else if (dir==2) row=pg[t]; else row=pg[L-1-t];
      float zv = __bfloat162float(szp[(size_t)row*512 + d]);
      xcp[(size_t)t*512 + d] = (y + xv*dp) * zv;
    }
  }
}

// ---------------- build [f|b] concat matrices for gating ----------------
__global__ __launch_bounds__(256) void gatecat_kernel(const float* __restrict__ o0, const float* __restrict__ o1,
    const float* __restrict__ o2, const float* __restrict__ o3,
    float* __restrict__ ufub, float* __restrict__ sfsb){
  int i = blockIdx.x, g = blockIdx.y, d = threadIdx.x;
  size_t rf = (size_t)(g*L+i);
  size_t rb = (size_t)(g*L+(L-1-i));
  ufub[rf*512 + d]       = o0[rf*256+d];
  ufub[rf*512 + 256 + d] = o1[rb*256+d];
  sfsb[rf*512 + d]       = o2[rf*256+d];
  sfsb[rf*512 + 256 + d] = o3[rb*256+d];
}

__global__ __launch_bounds__(256) void unsort_kernel(const float* __restrict__ ysort, const int* __restrict__ inv, float* __restrict__ ydst){
  int i = blockIdx.x, g = blockIdx.y, d = threadIdx.x;
  int j = inv[g*L+i];
  ydst[(size_t)(g*L+i)*256+d] = ysort[(size_t)(g*L+j)*256+d];
}

// ---------------- layernorm (row of 256) ----------------
__global__ __launch_bounds__(256) void ln_kernel(const float* __restrict__ src, float* __restrict__ dst,
    const float* __restrict__ gam, const float* __restrict__ bet){
  __shared__ float red[256];
  int row = blockIdx.x, d = threadIdx.x;
  float v = src[(size_t)row*256+d];
  red[d]=v; __syncthreads();
  for (int s=128;s>0;s>>=1){ if (d<s) red[d]+=red[d+s]; __syncthreads(); }
  float m = red[0]*(1.f/256.f);
  __syncthreads();
  float c = v-m;
  red[d]=c*c; __syncthreads();
  for (int s=128;s>0;s>>=1){ if (d<s) red[d]+=red[d+s]; __syncthreads(); }
  float var = red[0]*(1.f/256.f);
  dst[(size_t)row*256+d] = c*rsqrtf(var+1e-5f)*gam[d]+bet[d];
}

// ---------------- softmax-2 weighted combine (pw / mc) ----------------
__global__ __launch_bounds__(256) void combine2_kernel(const float* __restrict__ u, const float* __restrict__ s,
    const float* __restrict__ W, const float* __restrict__ bb, float* __restrict__ out){
  int wv = threadIdx.x >> 6, lane = threadIdx.x & 63;
  int row = blockIdx.x*4 + wv;
  float a0=0.f, a1=0.f;
  float uv[4], sv[4];
  #pragma unroll
  for (int q=0;q<4;++q){
    int c = lane + q*64;
    float uu = u[(size_t)row*256+c], ss = s[(size_t)row*256+c];
    uv[q]=uu; sv[q]=ss;
    a0 = fmaf(uu, W[2*c], a0);   a0 = fmaf(ss, W[2*(c+256)], a0);
    a1 = fmaf(uu, W[2*c+1], a1); a1 = fmaf(ss, W[2*(c+256)+1], a1);
  }
  for (int o=32;o;o>>=1){ a0 += __shfl_xor(a0,o); a1 += __shfl_xor(a1,o); }
  a0 += bb[0]; a1 += bb[1];
  float mx = fmaxf(a0,a1);
  float e0 = __expf(a0-mx), e1 = __expf(a1-mx);
  float w0 = e0/(e0+e1), w1 = 1.f - w0;
  #pragma unroll
  for (int q=0;q<4;++q){
    int c = lane + q*64;
    out[(size_t)row*256+c] = w0*uv[q] + w1*sv[q];
  }
}

// ---------------- GCN layer-1 aggregation (512-wide, relu+deg-norm) ----------------
__global__ __launch_bounds__(256) void agg512_kernel(const float* __restrict__ m1, const int* __restrict__ off,
    const int* __restrict__ eid, const int* __restrict__ ei, const int* __restrict__ din,
    float* __restrict__ t1){
  int wv = threadIdx.x >> 6, lane = threadIdx.x & 63;
  int n = blockIdx.x*4 + wv;
  int c = lane*8;
  float4 A0 = {0,0,0,0}, A1 = {0,0,0,0};
  int p0 = off[n], p1 = off[n+1];
  for (int p=p0;p<p1;++p){
    int e = eid[p];
    int sN = ei[e];
    const float* rp = m1 + (size_t)sN*512 + c;
    float4 v0 = *(const float4*)rp, v1 = *(const float4*)(rp+4);
    A0.x+=v0.x; A0.y+=v0.y; A0.z+=v0.z; A0.w+=v0.w;
    A1.x+=v1.x; A1.y+=v1.y; A1.z+=v1.z; A1.w+=v1.w;
  }
  const float* sp = m1 + (size_t)n*512 + c;
  float4 v0 = *(const float4*)sp, v1 = *(const float4*)(sp+4);
  A0.x+=v0.x; A0.y+=v0.y; A0.z+=v0.z; A0.w+=v0.w;
  A1.x+=v1.x; A1.y+=v1.y; A1.z+=v1.z; A1.w+=v1.w;
  float sc = 1.f/((float)din[n]+1.f);
  float* op = t1 + (size_t)n*512 + c;
  op[0]=fmaxf(A0.x*sc,0.f); op[1]=fmaxf(A0.y*sc,0.f); op[2]=fmaxf(A0.z*sc,0.f); op[3]=fmaxf(A0.w*sc,0.f);
  op[4]=fmaxf(A1.x*sc,0.f); op[5]=fmaxf(A1.y*sc,0.f); op[6]=fmaxf(A1.z*sc,0.f); op[7]=fmaxf(A1.w*sc,0.f);
}

// ---------------- layer-2 projections (both chains, 4 outputs) ----------------
__global__ __launch_bounds__(256) void m2_kernel(const float* __restrict__ t1, const float* __restrict__ Wi,
    const float* __restrict__ Wo, float* __restrict__ m2){
  int wv = threadIdx.x>>6, lane = threadIdx.x&63;
  int row = blockIdx.x*4+wv;
  float a[4]={0,0,0,0};
  #pragma unroll
  for (int q=0;q<4;++q){
    int c = lane + q*64;
    float ti = t1[(size_t)row*512 + c];
    float to = t1[(size_t)row*512 + 256 + c];
    a[0]=fmaf(ti,Wi[2*c],a[0]); a[1]=fmaf(ti,Wi[2*c+1],a[1]);
    a[2]=fmaf(to,Wo[2*c],a[2]); a[3]=fmaf(to,Wo[2*c+1],a[3]);
  }
  for (int o=32;o;o>>=1){
    a[0]+=__shfl_xor(a[0],o); a[1]+=__shfl_xor(a[1],o);
    a[2]+=__shfl_xor(a[2],o); a[3]+=__shfl_xor(a[3],o);
  }
  if (lane==0){ float4 v={a[0],a[1],a[2],a[3]}; *(float4*)(m2+(size_t)row*4)=v; }
}

__global__ void p_kernel(const float* __restrict__ m2, const int* __restrict__ off, const int* __restrict__ eid,
    const int* __restrict__ ei, const int* __restrict__ din, float* __restrict__ pin, float* __restrict__ pout){
  int n = blockIdx.x*blockDim.x + threadIdx.x;
  if (n>=NN) return;
  float4 acc = *(const float4*)(m2 + (size_t)n*4);
  for (int p=off[n];p<off[n+1];++p){
    int e = eid[p]; int sN = ei[e];
    float4 v = *(const float4*)(m2+(size_t)sN*4);
    acc.x+=v.x; acc.y+=v.y; acc.z+=v.z; acc.w+=v.w;
  }
  float sc = 1.f/((float)din[n]+1.f);
  float a0=acc.x*sc, a1=acc.y*sc, b0=acc.z*sc, b1=acc.w*sc;
  {
    float mx=fmaxf(a0,a1); float e0=__expf(a0-mx), e1=__expf(a1-mx);
    pin[n] = e0/(e0+e1);
  }
  {
    float mx=fmaxf(b0,b1); float e0=__expf(b0-mx), e1=__expf(b1-mx);
    pout[n] = e0/(e0+e1);
  }
}

__global__ void ew_kernel(const int* __restrict__ ei, const float* __restrict__ pin, const float* __restrict__ pout,
    float* __restrict__ ew){
  int e = blockIdx.x*blockDim.x+threadIdx.x;
  if (e<EE) ew[e] = pin[ei[EE+e]] * pout[ei[e]];
}

// ---------------- weighted aggregation of edge_attr and m_env[src] ----------------
__global__ __launch_bounds__(256) void wagg_kernel(const float* __restrict__ eattr, const float* __restrict__ menv,
    const float* __restrict__ ew, const int* __restrict__ off, const int* __restrict__ eid,
    const int* __restrict__ ei, float* __restrict__ aat, float* __restrict__ aen){
  int wv=threadIdx.x>>6, lane=threadIdx.x&63;
  int n = blockIdx.x*4+wv;
  int c = lane*4;
  float4 A={0,0,0,0}, En={0,0,0,0};
  int p0=off[n], p1=off[n+1];
  for (int p=p0;p<p1;++p){
    int e = eid[p]; float w = ew[e]; int sN = ei[e];
    float4 av = *(const float4*)(eattr + (size_t)e*256 + c);
    float4 ev = *(const float4*)(menv + (size_t)sN*256 + c);
    A.x=fmaf(w,av.x,A.x); A.y=fmaf(w,av.y,A.y); A.z=fmaf(w,av.z,A.z); A.w=fmaf(w,av.w,A.w);
    En.x=fmaf(w,ev.x,En.x); En.y=fmaf(w,ev.y,En.y); En.z=fmaf(w,ev.z,En.z); En.w=fmaf(w,ev.w,En.w);
  }
  *(float4*)(aat+(size_t)n*256+c)=A;
  *(float4*)(aen+(size_t)n*256+c)=En;
}

// ---------------- cognn: combine + relu + LN ----------------
__global__ __launch_bounds__(256) void cognn_kernel(const float* __restrict__ aen, const float* __restrict__ aw,
    const float* __restrict__ menv, const int* __restrict__ din, const float* __restrict__ envb,
    const float* __restrict__ gam, const float* __restrict__ bet, float* __restrict__ out){
  __shared__ float red[256];
  int row=blockIdx.x, d=threadIdx.x;
  float sc = 1.f/((float)din[row]+1.f);
  float v = (aen[(size_t)row*256+d] + aw[(size_t)row*256+d] + menv[(size_t)row*256+d]) * sc + envb[d];
  v = fmaxf(v,0.f);
  red[d]=v; __syncthreads();
  for (int s=128;s>0;s>>=1){ if (d<s) red[d]+=red[d+s]; __syncthreads(); }
  float m = red[0]*(1.f/256.f);
  __syncthreads();
  float c = v-m;
  red[d]=c*c; __syncthreads();
  for (int s=128;s>0;s>>=1){ if (d<s) red[d]+=red[d+s]; __syncthreads(); }
  float var = red[0]*(1.f/256.f);
  out[(size_t)row*256+d] = c*rsqrtf(var+1e-5f)*gam[d]+bet[d];
}

// =====================================================================
extern "C" void kernel_launch(void* const* d_in, const int* in_sizes, int n_in,
                              void* d_out, int out_size, void* d_ws, size_t ws_size,
                              hipStream_t stream) {
  const float* x       = (const float*)d_in[0];
  const int*   ei      = (const int*)d_in[1];
  const float* eattr   = (const float*)d_in[2];
  const float* m_Win   = (const float*)d_in[4];
  const float* m_convw = (const float*)d_in[5];
  const float* m_convb = (const float*)d_in[6];
  const float* m_Wx    = (const float*)d_in[7];
  const float* m_Wdt   = (const float*)d_in[8];
  const float* m_bdt   = (const float*)d_in[9];
  const float* m_Alog  = (const float*)d_in[10];
  const float* m_Dp    = (const float*)d_in[11];
  const float* m_Wout  = (const float*)d_in[12];
  const float* gate_u_W= (const float*)d_in[13];
  const float* gate_u_b= (const float*)d_in[14];
  const float* gate_s_W= (const float*)d_in[15];
  const float* gate_s_b= (const float*)d_in[16];
  const float* fn_g    = (const float*)d_in[17];
  const float* fn_b    = (const float*)d_in[18];
  const float* on_g    = (const float*)d_in[19];
  const float* on_b    = (const float*)d_in[20];
  const float* pw_W    = (const float*)d_in[21];
  const float* pw_b    = (const float*)d_in[22];
  const float* mc_W    = (const float*)d_in[23];
  const float* mc_b    = (const float*)d_in[24];
  const float* ca_W1   = (const float*)d_in[25];
  const float* ca_b1   = (const float*)d_in[26];
  const float* ca_W2   = (const float*)d_in[27];
  const float* ca_b2   = (const float*)d_in[28];
  const float* fe_W1   = (const float*)d_in[29];
  const float* fe_b1   = (const float*)d_in[30];
  const float* fe_W2   = (const float*)d_in[31];
  const float* fe_b2   = (const float*)d_in[32];
  const float* in_W1   = (const float*)d_in[33];
  const float* in_W2   = (const float*)d_in[34];
  const float* out_W1  = (const float*)d_in[35];
  const float* out_W2  = (const float*)d_in[36];
  const float* env_W   = (const float*)d_in[37];
  const float* env_b   = (const float*)d_in[38];
  const float* edge_W  = (const float*)d_in[39];

  char* w = (char*)d_ws;
  size_t o = 0;
  auto alignup = [&](){ o = (o + 255) & ~(size_t)255; };
  auto F = [&](size_t n){ alignup(); float* p=(float*)(w+o); o+=n*sizeof(float); return p; };
  auto Ii = [&](size_t n){ alignup(); int* p=(int*)(w+o); o+=n*sizeof(int); return p; };

  int* deg_out = Ii(NN);
  int* deg_in  = Ii(NN);
  int* permB   = Ii(NN);
  int* invB    = Ii(NN);
  int* csr_off = Ii(NN+1);
  int* csr_cur = Ii(NN);
  int* csr_eid = Ii(EE);
  float* ew    = F(EE);
  float* m2cat = F((size_t)NN*4);
  float* p_in  = F(NN);
  float* p_out = F(NN);
  float* a1b   = F((size_t)NN*64);
  float* dbl4  = F((size_t)4*NN*48);
  float* outs  = F((size_t)NN*1024);
  // ---- aliased region: mamba phase [xc4 | sz4(bf16) | xz] ; post phase [A0..A3 | bufB | bufC]
  alignup();
  char* region = w + o;
  float*          xc4 = (float*)region;                                         // 4*NN*512 f32 (256MB)
  __hip_bfloat16* sz4 = (__hip_bfloat16*)(region + (size_t)4*NN*512*4);         // 4*NN*512 bf16 (128MB)
  float*          xz  = (float*)(region + (size_t)4*NN*512*4 + (size_t)4*NN*512*2); // NN*1024 f32 (128MB)
  o += (size_t)4*NN*512*4 + (size_t)4*NN*512*2 + (size_t)NN*1024*4;
  // post-phase aliases (xc4 is dead after the Wout GEMMs)
  float* A0 = (float*)region;                  // NN*256 each
  float* A1 = A0 + (size_t)NN*256;
  float* A2 = A0 + (size_t)NN*512;
  float* A3 = A0 + (size_t)NN*768;
  float* bufB = (float*)region + (size_t)NN*1024;   // NN*512
  float* bufC = bufB + (size_t)NN*512;              // NN*512
  float* O0 = outs;
  float* O1 = outs + (size_t)NN*256;
  float* O2 = outs + (size_t)NN*512;
  float* O3 = outs + (size_t)NN*768;

  // ---- graph structure ----
  hipMemsetAsync(deg_out, 0, NN*sizeof(int), stream);
  hipMemsetAsync(deg_in,  0, NN*sizeof(int), stream);
  hipMemsetAsync(csr_cur, 0, NN*sizeof(int), stream);
  deg_kernel<<<EE/256, 256, 0, stream>>>(ei, deg_out, deg_in);
  sort_kernel<<<G, 512, 0, stream>>>(deg_out, permB, invB);
  prefix_kernel<<<1, 1024, 0, stream>>>(deg_in, csr_off, NN);
  csr_fill<<<EE/256, 256, 0, stream>>>(ei, csr_off, csr_cur, csr_eid);

  // ---- mamba: stage-wise over 4 directions, ONE batched scan ----
  for (int k=0;k<4;++k){
    gemm_k<<<dim3(16,512), 256, 0, stream>>>(x, m_Win + (size_t)k*256*1024,
        nullptr, nullptr, nullptr, nullptr, xz, 1024, 256, 256, 1024, 0);
    conv_kernel<<<dim3(L,G), 512, 0, stream>>>(xz, m_convw + (size_t)k*512*4,
        m_convb + (size_t)k*512, permB, xc4 + (size_t)k*NN*512, sz4 + (size_t)k*NN*512, k);
    gemm_k<<<dim3(1,512), 256, 0, stream>>>(xc4 + (size_t)k*NN*512, m_Wx + (size_t)k*512*48,
        nullptr, nullptr, nullptr, nullptr, dbl4 + (size_t)k*NN*48, 48, 512, 512, 48, 0);
  }
  scan4_kernel<<<dim3(4,G,4), 256, 0, stream>>>(xc4, dbl4, sz4, m_Wdt, m_bdt, m_Alog, m_Dp, permB);
  for (int k=0;k<4;++k){
    gemm_k<<<dim3(4,512), 256, 0, stream>>>(xc4 + (size_t)k*NN*512, m_Wout + (size_t)k*512*256,
        nullptr, nullptr, nullptr, nullptr, outs + (size_t)k*NN*256, 256, 512, 512, 256, 0);
  }

  // ---- bidirectional gating ----
  gatecat_kernel<<<dim3(L,G), 256, 0, stream>>>(O0, O1, O2, O3, bufB, bufC);
  gemm_k<<<dim3(4,512), 256, 0, stream>>>(bufB, gate_u_W, gate_u_b, nullptr, nullptr, bufB,
      A0, 256, 512, 512, 256, 3);                         // y_u
  gemm_k<<<dim3(4,512), 256, 0, stream>>>(bufC, gate_s_W, gate_s_b, nullptr, nullptr, bufC,
      A1, 256, 512, 512, 256, 3);                         // y_s_sorted
  unsort_kernel<<<dim3(L,G), 256, 0, stream>>>(A1, invB, A2);  // y_s
  ln_kernel<<<NN, 256, 0, stream>>>(A0, O0, fn_g, fn_b);       // unsorted_out
  ln_kernel<<<NN, 256, 0, stream>>>(A2, O1, fn_g, fn_b);       // sorted_out
  combine2_kernel<<<NN/4, 256, 0, stream>>>(O0, O1, pw_W, pw_b, A3);  // mamba_out

  // ---- GCN probability chains ----
  gemm_k<<<dim3(4,512), 256, 0, stream>>>(x, in_W1, nullptr, nullptr, nullptr, nullptr,
      bufB, 256, 256, 256, 512, 0);
  gemm_k<<<dim3(4,512), 256, 0, stream>>>(x, out_W1, nullptr, nullptr, nullptr, nullptr,
      bufB + 256, 256, 256, 256, 512, 0);
  agg512_kernel<<<NN/4, 256, 0, stream>>>(bufB, csr_off, csr_eid, ei, deg_in, bufC);
  m2_kernel<<<NN/4, 256, 0, stream>>>(bufC, in_W2, out_W2, m2cat);
  p_kernel<<<NN/256, 256, 0, stream>>>(m2cat, csr_off, csr_eid, ei, deg_in, p_in, p_out);

  // ---- CoGNN environment branch ----
  gemm_k<<<dim3(4,512), 256, 0, stream>>>(x, env_W, nullptr, nullptr, nullptr, nullptr,
      O0, 256, 256, 256, 256, 0);                        // m_env
  ew_kernel<<<EE/256, 256, 0, stream>>>(ei, p_in, p_out, ew);
  wagg_kernel<<<NN/4, 256, 0, stream>>>(eattr, O0, ew, csr_off, csr_eid, ei, O1, O2); // agg_attr, agg_env
  gemm_k<<<dim3(4,512), 256, 0, stream>>>(O1, edge_W, nullptr, nullptr, nullptr, nullptr,
      O3, 256, 256, 256, 256, 0);                        // agg_attr @ edge_W
  cognn_kernel<<<NN, 256, 0, stream>>>(O2, O3, O0, deg_in, env_b, fn_g, fn_b, A0); // cognn

  // ---- channel attention + fusion ----
  gemm_k<<<dim3(1,512), 256, 0, stream>>>(A3, ca_W1, ca_b1, nullptr, nullptr, nullptr,
      a1b, 64, 256, 256, 64, 1);
  gemm_k<<<dim3(4,512), 256, 0, stream>>>(a1b, ca_W2, ca_b2, nullptr, A3, nullptr,
      bufB, 256, 64, 64, 256, 2);                        // mo
  gemm_k<<<dim3(1,512), 256, 0, stream>>>(A0, ca_W1, ca_b1, nullptr, nullptr, nullptr,
      a1b, 64, 256, 256, 64, 1);
  gemm_k<<<dim3(4,512), 256, 0, stream>>>(a1b, ca_W2, ca_b2, nullptr, A0, nullptr,
      bufB + (size_t)NN*256, 256, 64, 64, 256, 2);       // co
  combine2_kernel<<<NN/4, 256, 0, stream>>>(bufB, bufB + (size_t)NN*256, mc_W, mc_b, O0); // out

  // ---- feedforward + residual + final LN ----
  gemm_k<<<dim3(4,512), 256, 0, stream>>>(O0, fe_W1, fe_b1, nullptr, nullptr, nullptr,
      O1, 256, 256, 256, 256, 1);
  gemm_k<<<dim3(4,512), 256, 0, stream>>>(O1, fe_W2, fe_b2, x, nullptr, nullptr,
      A1, 256, 256, 256, 256, 0);
  ln_kernel<<<NN, 256, 0, stream>>>(A1, (float*)d_out, on_g, on_b);
}